// Round 12
// baseline (266.502 us; speedup 1.0000x reference)
//
#include <hip/hip_runtime.h>
#include <hip/hip_bf16.h>
#include <math.h>

typedef __attribute__((ext_vector_type(8))) short bf16x8;
typedef __attribute__((ext_vector_type(4))) float f32x4;
typedef __attribute__((ext_vector_type(2))) float f32x2;

#define MROWS 12544      // (128+128)*49
#define CDIM 768
#define INNER 96
#define S49 49
#define NSIDE 6272       // 128*49 rows per side
#define SCALE 0.10206207261596577f
// SCALE * log2(e): Q prescale so attn can use exp2 directly
#define SCALE_EXP2 ((float)(0.10206207261596577 * 1.4426950408889634))

__device__ __forceinline__ unsigned short f2bf(float f) {
  union { float f; unsigned u; } v; v.f = f;
  unsigned u = v.u;
  return (unsigned short)((u + 0x7fffu + ((u >> 16) & 1u)) >> 16);
}
__device__ __forceinline__ float bf2f(unsigned short h) {
  union { unsigned u; float f; } v; v.u = ((unsigned)h) << 16;
  return v.f;
}
// pack two floats to bf16x2 (round-to-nearest-ish): low=a, high=b
__device__ __forceinline__ unsigned pack_bf16_rn(float a, float b) {
  union { float f; unsigned u; } ua, ub; ua.f = a; ub.f = b;
  return __builtin_amdgcn_perm(ub.u + 0x8000u, ua.u + 0x8000u, 0x07060302u);
}

// async global->LDS, 16B per lane. Dest must be wave-uniform base + lane*16.
__device__ __forceinline__ void gld16(const unsigned short* g, unsigned short* l) {
  __builtin_amdgcn_global_load_lds(
      (const __attribute__((address_space(1))) unsigned int*)(g),
      (__attribute__((address_space(3))) unsigned int*)(l), 16, 0, 0);
}

// ---------------------------------------------------------------------------
// prep_all: one kernel, three phases by block range.
// ---------------------------------------------------------------------------
__global__ __launch_bounds__(256) void prep_all(
    const float* __restrict__ fa, const float* __restrict__ fb,
    const float* __restrict__ w10, const float* __restrict__ w11,
    const float* __restrict__ w12, const float* __restrict__ w20,
    const float* __restrict__ w21, const float* __restrict__ w22,
    unsigned short* __restrict__ X,
    unsigned short* __restrict__ W1T, unsigned short* __restrict__ W2T,
    unsigned short* __restrict__ VtKpad) {
  const int t = threadIdx.x;
  int id = blockIdx.x;
  if (id < 3072) {
    __shared__ float T[64][50];
    const int z = id / 1536; id -= z * 1536;
    const int ct = id % 12, img = id / 12;
    const float* feat = z ? fb : fa;
    const float* src = feat + (size_t)img * (CDIM * S49) + (size_t)ct * 64 * S49;
    for (int idx = t; idx < 64 * S49; idx += 256) {
      int cc = idx / S49, s = idx - cc * S49;
      T[cc][s] = src[cc * S49 + s];
    }
    __syncthreads();
    unsigned short* dst = X + (size_t)(z * 128 + img) * S49 * CDIM + ct * 64;
    for (int idx = t; idx < S49 * 64; idx += 256) {
      int s = idx >> 6, cc = idx & 63;
      dst[(size_t)s * CDIM + cc] = f2bf(T[cc][s]);
    }
  } else if (id < 5016) {
    __shared__ float T[32][33];
    id -= 3072;
    const float* src;
    unsigned short* dst;
    int C, ctile, rtile;
    if (id < 1728) {
      int wdx = id / 576, tid = id - wdx * 576;
      ctile = tid % 24; rtile = tid / 24;
      src = wdx == 0 ? w10 : (wdx == 1 ? w11 : w12);
      dst = W1T + (size_t)wdx * CDIM * CDIM;
      C = CDIM;
    } else {
      id -= 1728;
      int wdx = id / 72, tid = id - wdx * 72;
      ctile = tid % 3; rtile = tid / 3;
      src = wdx == 0 ? w20 : (wdx == 1 ? w21 : w22);
      dst = W2T + (size_t)wdx * INNER * CDIM;
      C = INNER;
    }
    const int c0 = ctile * 32, r0 = rtile * 32;
    for (int idx = t; idx < 1024; idx += 256) {
      int rr = idx >> 5, cc = idx & 31;
      T[rr][cc] = src[(size_t)(r0 + rr) * C + c0 + cc];
    }
    __syncthreads();
    for (int idx = t; idx < 1024; idx += 256) {
      int rr = idx >> 5, cc = idx & 31;
      dst[(size_t)(c0 + rr) * CDIM + r0 + cc] = f2bf(T[cc][rr]);
    }
  } else {
    id -= 5016;
    ushort4* p4 = (ushort4*)VtKpad;
    const ushort4 z = make_ushort4(0, 0, 0, 0);
#pragma unroll
    for (int i = 0; i < 32; i++)
      p4[(size_t)id * 8192 + i * 256 + t] = z;
  }
}

// ---------------------------------------------------------------------------
// gemm1f: per block (n-slice sl, m-tile, wdx):
//   (1) 8-phase 256x256 BK=64 counted-vmcnt loop (R10-verified), OPERAND-
//       SWAPPED (D[n][m]: thread holds 4 consecutive n) so the H-tile packs
//       into 8B ds_writes. Stage slots re-derived disjoint-per-phase:
//       ph0->A1(t+1) ph1->B1(t+1) ph2->A0(t+2) ph3->B0(t+2); vmcnt(4) at
//       ph3 lands tile t+1 (queue algebra identical to R10).
//   (2) relu+pack -> H-tile (256x256 bf16 = 128KB) into L (dead after loop),
//       chunk-swizzle c^=(m&7), 2-way banks on write and read.
//   (3) mini-GEMM Opart[sl] = H @ W2slice (256x96, K=256): a-frags from LDS,
//       b-frags streamed from L2-hot W2T (48KB/slice shared by 49 blocks).
// H never touches HBM; gemm2's kernel+staging deleted (finalize sums slices).
// ---------------------------------------------------------------------------
#define BARR() do { __builtin_amdgcn_sched_barrier(0); \
  __builtin_amdgcn_s_barrier(); __builtin_amdgcn_sched_barrier(0); } while (0)
#define STG(src, dhalf) do { \
  gld16((src), (dhalf) + t8); \
  gld16((src) + 32, (dhalf) + t8 + 4096); } while (0)
#define MFMA_QUAD(QN, QM) do { \
  __builtin_amdgcn_s_setprio(1); \
  _Pragma("unroll") \
  for (int ni = 0; ni < 4; ++ni) { \
    _Pragma("unroll") \
    for (int mi = 0; mi < 2; ++mi) { \
      _Pragma("unroll") \
      for (int ks = 0; ks < 2; ++ks) \
        acc[(QN)*4+ni][(QM)*2+mi] = __builtin_amdgcn_mfma_f32_16x16x32_bf16( \
            Af[ni*2+ks], Bf[mi*2+ks], acc[(QN)*4+ni][(QM)*2+mi], 0, 0, 0); \
    } \
  } \
  __builtin_amdgcn_s_setprio(0); } while (0)

__global__ __launch_bounds__(512, 2) void gemm1f(
    const unsigned short* __restrict__ X,
    const unsigned short* __restrict__ W1T,
    const unsigned short* __restrict__ W2T,
    float* __restrict__ Opart) {
  __shared__ __align__(16) unsigned short L[2][4][8192];  // 128 KB
  unsigned short* Hl = &L[0][0][0];                       // aliased H-tile
  const int t = threadIdx.x;
  const int lane = t & 63, w = t >> 6;
  const int lr = lane & 15, lq = lane >> 4;
  const int wn2 = w >> 2, wm4 = w & 3;     // n-half (128), m-quarter (64)
  // ---- bijective XCD swizzle over the full grid (m204 formula)
  const int gx = gridDim.x, gxy = gx * gridDim.y;
  const int nwg = gxy * gridDim.z;
  const int orig = blockIdx.x + gx * (blockIdx.y + gridDim.y * blockIdx.z);
  const int q8 = nwg >> 3, r8 = nwg & 7;
  const int xcd = orig & 7, rank = orig >> 3;
  const int logical = (xcd < r8 ? xcd * (q8 + 1) : r8 * (q8 + 1) + (xcd - r8) * q8) + rank;
  const int wdx = logical / gxy;
  const int rem = logical - wdx * gxy;
  const int M0 = (rem / gx) * 256, sl = rem % gx, N0 = sl * 256;
  const unsigned short* W1w = W1T + (size_t)wdx * CDIM * CDIM;
  const unsigned short* W2w = W2T + (size_t)wdx * INNER * CDIM;

  // ---- staging source (per-thread): identical to R10 kernel
  const int rs = t >> 2;
  const int cs = ((t & 3) * 8) ^ (((rs >> 3) & 1) << 4);
  const int soff = rs * CDIM + cs;
  const unsigned short* pA0 = X + (size_t)M0 * CDIM + soff;
  const unsigned short* pA1 = pA0 + (size_t)128 * CDIM;
  const unsigned short* pB0 = W1w + (size_t)N0 * CDIM + soff;
  const unsigned short* pB1 = pB0 + (size_t)128 * CDIM;
  const int t8 = t * 8;

  // ---- ds_read base (same involution as the source preswizzle)
  const int rdbase = lr * 32 + ((lq * 8) ^ (((lr >> 3) & 1) << 4));
  const int aoff = (wm4 & 1) * 2048;  // row offset within X region (64 rows)

  const f32x4 z4 = {0.f, 0.f, 0.f, 0.f};
  f32x4 acc[8][4];                    // acc[nfr][mfr], D[n][m]
#pragma unroll
  for (int i = 0; i < 8; ++i)
#pragma unroll
    for (int j = 0; j < 4; ++j) acc[i][j] = z4;
  bf16x8 Af[8], Bf[8];

  // ---- prologue: tile0 {A0,A1,B0,B1}, tile1 {A0,B0}; land tile0.
  STG(pA0, &L[0][0][0]);
  STG(pA1, &L[0][1][0]);
  STG(pB0, &L[0][2][0]);
  STG(pB1, &L[0][3][0]);
  STG(pA0 + 64, &L[1][0][0]);
  STG(pB0 + 64, &L[1][2][0]);
  asm volatile("s_waitcnt vmcnt(4)" ::: "memory");
  BARR();

  for (int tau = 0; tau < 12; ++tau) {
    const int buf = tau & 1;
    const unsigned short* LBa = &L[buf][2 + wn2][0];        // W1 (a-side)
    const unsigned short* LAb = &L[buf][wm4 >> 1][0];       // X  (b-side)
    // ---- phase 0: read a(nfr0-3) + b(mfr0-1); stage A1(tau+1)
#pragma unroll
    for (int ni = 0; ni < 4; ++ni)
#pragma unroll
      for (int ks = 0; ks < 2; ++ks)
        Af[ni * 2 + ks] = *(const bf16x8*)(LBa + ks * 4096 + ni * 512 + rdbase);
#pragma unroll
    for (int mi = 0; mi < 2; ++mi)
#pragma unroll
      for (int ks = 0; ks < 2; ++ks)
        Bf[mi * 2 + ks] = *(const bf16x8*)(LAb + ks * 4096 + aoff + mi * 512 + rdbase);
    if (tau + 1 < 12) STG(pA1 + (tau + 1) * 64, &L[(tau + 1) & 1][1][0]);
    BARR();
    MFMA_QUAD(0, 0);
    BARR();
    // ---- phase 1: read b(mfr2-3); stage B1(tau+1)
#pragma unroll
    for (int mi = 0; mi < 2; ++mi)
#pragma unroll
      for (int ks = 0; ks < 2; ++ks)
        Bf[4 + mi * 2 + ks] = *(const bf16x8*)(LAb + ks * 4096 + aoff + (2 + mi) * 512 + rdbase);
    if (tau + 1 < 12) STG(pB1 + (tau + 1) * 64, &L[(tau + 1) & 1][3][0]);
    BARR();
    {
      __builtin_amdgcn_s_setprio(1);
#pragma unroll
      for (int ni = 0; ni < 4; ++ni)
#pragma unroll
        for (int mi = 0; mi < 2; ++mi)
#pragma unroll
          for (int ks = 0; ks < 2; ++ks)
            acc[ni][2 + mi] = __builtin_amdgcn_mfma_f32_16x16x32_bf16(
                Af[ni * 2 + ks], Bf[4 + mi * 2 + ks], acc[ni][2 + mi], 0, 0, 0);
      __builtin_amdgcn_s_setprio(0);
    }
    BARR();
    // ---- phase 2: read a(nfr4-7); stage A0(tau+2) (A reads ended ph1)
#pragma unroll
    for (int ni = 0; ni < 4; ++ni)
#pragma unroll
      for (int ks = 0; ks < 2; ++ks)
        Af[ni * 2 + ks] = *(const bf16x8*)(LBa + ks * 4096 + (4 + ni) * 512 + rdbase);
    if (tau + 2 < 12) STG(pA0 + (tau + 2) * 64, &L[buf][0][0]);
    BARR();
    MFMA_QUAD(1, 0);
    BARR();
    // ---- phase 3: stage B0(tau+2); counted vmcnt lands tile tau+1
    if (tau + 2 < 12) STG(pB0 + (tau + 2) * 64, &L[buf][2][0]);
    if (tau < 10) {
      asm volatile("s_waitcnt vmcnt(4)" ::: "memory");
    } else if (tau == 10) {
      asm volatile("s_waitcnt vmcnt(0)" ::: "memory");
    }
    BARR();
    {
      __builtin_amdgcn_s_setprio(1);
#pragma unroll
      for (int ni = 0; ni < 4; ++ni)
#pragma unroll
        for (int mi = 0; mi < 2; ++mi)
#pragma unroll
          for (int ks = 0; ks < 2; ++ks)
            acc[4 + ni][2 + mi] = __builtin_amdgcn_mfma_f32_16x16x32_bf16(
                Af[ni * 2 + ks], Bf[4 + mi * 2 + ks], acc[4 + ni][2 + mi], 0, 0, 0);
      __builtin_amdgcn_s_setprio(0);
    }
    BARR();
  }

  // ---- H-tile publish: relu + pack 4 consecutive n -> Hl[m][n] (c^=(m&7))
#pragma unroll
  for (int nfr = 0; nfr < 8; ++nfr)
#pragma unroll
    for (int mfr = 0; mfr < 4; ++mfr) {
      int m = wm4 * 64 + mfr * 16 + lr;
      int nb = wn2 * 128 + nfr * 16 + lq * 4;
      int c = (nb >> 3) ^ (m & 7);
      f32x4 v = acc[nfr][mfr];
      uint2 pk = make_uint2(pack_bf16_rn(fmaxf(v[0], 0.f), fmaxf(v[1], 0.f)),
                            pack_bf16_rn(fmaxf(v[2], 0.f), fmaxf(v[3], 0.f)));
      *(uint2*)(Hl + m * 256 + c * 8 + (lq & 1) * 4) = pk;
    }
  __syncthreads();

  // ---- mini-GEMM: Opart = H(256x256) @ W2slice(256x96)
  const int wmo = w >> 1, weo = w & 1;   // m-quarter (64), e-half (48)
  f32x4 acc2[4][3];
#pragma unroll
  for (int i = 0; i < 4; ++i)
#pragma unroll
    for (int j = 0; j < 3; ++j) acc2[i][j] = z4;
#pragma unroll
  for (int ks = 0; ks < 8; ++ks) {
    bf16x8 a[4], b[3];
#pragma unroll
    for (int mf = 0; mf < 4; ++mf) {
      int m = wmo * 64 + mf * 16 + lr;
      int cc = (ks * 4 + lq) ^ (m & 7);
      a[mf] = *(const bf16x8*)(Hl + m * 256 + cc * 8);
    }
#pragma unroll
    for (int ef = 0; ef < 3; ++ef) {
      int e = weo * 48 + ef * 16 + lr;
      b[ef] = *(const bf16x8*)(W2w + (size_t)e * CDIM + N0 + ks * 32 + lq * 8);
    }
#pragma unroll
    for (int mf = 0; mf < 4; ++mf)
#pragma unroll
      for (int ef = 0; ef < 3; ++ef)
        acc2[mf][ef] = __builtin_amdgcn_mfma_f32_16x16x32_bf16(a[mf], b[ef], acc2[mf][ef], 0, 0, 0);
  }
  // ---- store partial O (f32): rows m = ..lq*4+r, cols e = ..lr
  float* Op = Opart + ((size_t)(sl * 3 + wdx) * MROWS + M0) * INNER;
#pragma unroll
  for (int mf = 0; mf < 4; ++mf)
#pragma unroll
    for (int ef = 0; ef < 3; ++ef)
#pragma unroll
      for (int r = 0; r < 4; ++r) {
        int m = wmo * 64 + mf * 16 + lq * 4 + r;
        int e = weo * 48 + ef * 16 + lr;
        Op[(size_t)m * INNER + e] = acc2[mf][ef][r];
      }
}

// ---------------------------------------------------------------------------
// finalize: O = sum of 3 slice-partials; epilogue = gemm2b5's (Q prescale /
// Kpad / Vt + vnorm). Grid (196, 3), 256 thr; thread = (m_local = t>>2,
// e-quarter = t&3 -> 24 e).
// ---------------------------------------------------------------------------
__global__ __launch_bounds__(256) void finalize(const float* __restrict__ Opart,
                                                unsigned short* __restrict__ QKV,
                                                unsigned short* __restrict__ Kpad,
                                                unsigned short* __restrict__ Vt,
                                                float* __restrict__ vnorm) {
  const int t = threadIdx.x;
  const int m0 = blockIdx.x * 64, wdx = blockIdx.y;
  const int ml = t >> 2, eq = t & 3;
  const int m = m0 + ml;
  const int e0 = eq * 24;
  float o[24];
#pragma unroll
  for (int s = 0; s < 3; ++s) {
    const float* src = Opart + ((size_t)(s * 3 + wdx) * MROWS + m) * INNER + e0;
#pragma unroll
    for (int j = 0; j < 6; ++j) {
      float4 v = *(const float4*)(src + j * 4);
      if (s == 0) { o[j*4] = v.x; o[j*4+1] = v.y; o[j*4+2] = v.z; o[j*4+3] = v.w; }
      else { o[j*4] += v.x; o[j*4+1] += v.y; o[j*4+2] += v.z; o[j*4+3] += v.w; }
    }
  }
  const int img = m / 49, s49 = m - img * 49;
  float nsq = 0.f;
#pragma unroll
  for (int j = 0; j < 24; ++j) {
    int e = e0 + j;
    float v = o[j];
    if (wdx == 0) {
      QKV[(size_t)m * INNER + e] = f2bf(v * SCALE_EXP2);
    } else if (wdx == 1) {
      Kpad[(size_t)(img * 64 + s49) * INNER + e] = f2bf(v);
    } else {
      QKV[(size_t)(2 * MROWS + m) * INNER + e] = f2bf(v);
      Vt[(size_t)img * (INNER * 64) + e * 64 + s49] = f2bf(v);
      nsq += v * v;
    }
  }
  if (wdx == 2) {
    nsq += __shfl_xor(nsq, 1, 64);
    nsq += __shfl_xor(nsq, 2, 64);
    if (eq == 0) vnorm[m] = sqrtf(nsq);
  }
}

// ---------------------------------------------------------------------------
// attn13 (verified ~90us): K single-buffered, Vt async-staged to LDS,
// 2 barriers/fi, LDS 40960B, grid 1568, setprio on MFMA, pk_fma epilogue.
// ---------------------------------------------------------------------------
__global__ __launch_bounds__(256) void attn13(const unsigned short* __restrict__ Qp,
                                              const unsigned short* __restrict__ Kpad,
                                              const unsigned short* __restrict__ V,
                                              const unsigned short* __restrict__ Vt,
                                              const float* __restrict__ vnorm,
                                              float* __restrict__ cosbuf) {
  __shared__ __align__(16) unsigned short Ks[64 * INNER];      // 12 KB
  __shared__ __align__(16) unsigned short VtS[INNER * 64];     // 12 KB
  __shared__ __align__(16) unsigned short Ps[4][32 * 64];      // 16 KB

  const int t = threadIdx.x;
  const int lane = t & 63, w = t >> 6;
  const int lr = lane & 15, lq = lane >> 4;
  const f32x4 z4 = {0.f, 0.f, 0.f, 0.f};

  int bx = blockIdx.x;
  const int dir = bx / 784; bx -= dir * 784;     // 784 = 49 chunks * 16 fgroups
  const int chunk = bx >> 4, fg = bx & 15;
  const int r0 = chunk * 128;
  const int qbase = dir * NSIDE;

  int goK[3], goV[3], lo[3];
#pragma unroll
  for (int j = 0; j < 3; j++) {
    int l = (w * 3 + j) * 64 + lane;
    lo[j] = l * 8;
    int rK = l / 12, scK = l - rK * 12;
    int ccK = scK - ((rK >> 1) & 7); if (ccK < 0) ccK += 12;
    goK[j] = rK * INNER + ccK * 8;
    int rV = l >> 3, scV = l & 7;
    int ccV = (scV - (rV & 7)) & 7;
    goV[j] = rV * 64 + ccV * 8;
  }
  int rdK[3], rdV[2];
#pragma unroll
  for (int ks = 0; ks < 3; ks++) {
    int sc = (ks * 4 + lq + ((lr >> 1) & 7)) % 12;
    rdK[ks] = lr * INNER + sc * 8;
  }
#pragma unroll
  for (int ks = 0; ks < 2; ks++) {
    int sc = (ks * 4 + lq + (lr & 7)) & 7;
    rdV[ks] = lr * 64 + sc * 8;
  }

  bf16x8 qf[2][3];
#pragma unroll
  for (int qt = 0; qt < 2; qt++) {
    const int qrow = qbase + r0 + w * 32 + qt * 16 + lr;
#pragma unroll
    for (int ks = 0; ks < 3; ks++)
      qf[qt][ks] = *(const bf16x8*)(Qp + (size_t)qrow * INNER + ks * 32 + lq * 8);
  }
  f32x2 rv2[2][6][2];
  float invvn[2];
#pragma unroll
  for (int qt = 0; qt < 2; qt++) {
    const int qrow = qbase + r0 + w * 32 + qt * 16 + lr;
    invvn[qt] = 1.f / fmaxf(vnorm[qrow], 1e-8f);
#pragma unroll
    for (int et = 0; et < 6; et++) {
      ushort4 u = *(const ushort4*)(V + (size_t)qrow * INNER + et * 16 + lq * 4);
      rv2[qt][et][0] = (f32x2){bf2f(u.x), bf2f(u.y)};
      rv2[qt][et][1] = (f32x2){bf2f(u.z), bf2f(u.w)};
    }
  }

  unsigned short* Pw = &Ps[w][0];
  const int kimg0 = (dir == 0 ? 128 : 0) + fg * 8;
  {
    const unsigned short* kg = Kpad + (size_t)kimg0 * (64 * INNER);
#pragma unroll
    for (int j = 0; j < 3; j++) gld16(kg + goK[j], Ks + lo[j]);
  }
  for (int fi = 0; fi < 8; fi++) {
    const int f = fg * 8 + fi;
    __syncthreads();   // (1) drains K[fi]; prev PV done by all waves
    {
      const unsigned short* vg = Vt + (size_t)(kimg0 + fi) * (INNER * 64);
#pragma unroll
      for (int j = 0; j < 3; j++) gld16(vg + goV[j], VtS + lo[j]);
    }
    f32x4 s4[2][4] = {{z4, z4, z4, z4}, {z4, z4, z4, z4}};
    __builtin_amdgcn_s_setprio(1);
#pragma unroll
    for (int ks = 0; ks < 3; ks++) {
#pragma unroll
      for (int kt = 0; kt < 4; kt++) {
        bf16x8 a = *(const bf16x8*)(Ks + kt * (16 * INNER) + rdK[ks]);
        s4[0][kt] = __builtin_amdgcn_mfma_f32_16x16x32_bf16(a, qf[0][ks], s4[0][kt], 0, 0, 0);
        s4[1][kt] = __builtin_amdgcn_mfma_f32_16x16x32_bf16(a, qf[1][ks], s4[1][kt], 0, 0, 0);
      }
    }
    __builtin_amdgcn_s_setprio(0);
#pragma unroll
    for (int qt = 0; qt < 2; qt++)
#pragma unroll
      for (int kt = 0; kt < 4; kt++) {
        float e0 = __builtin_exp2f(s4[qt][kt][0]);
        float e1 = __builtin_exp2f(s4[qt][kt][1]);
        float e2 = __builtin_exp2f(s4[qt][kt][2]);
        float e3 = __builtin_exp2f(s4[qt][kt][3]);
        unsigned lopk, hipk;
        asm("v_cvt_pk_bf16_f32 %0, %1, %2" : "=v"(lopk) : "v"(e0), "v"(e1));
        asm("v_cvt_pk_bf16_f32 %0, %1, %2" : "=v"(hipk) : "v"(e2), "v"(e3));
        uint2 pk = make_uint2(lopk, hipk);
        int row = qt * 16 + lr;
        int ch = (2 * kt + (lq >> 1)) ^ (row & 7);
        *(uint2*)(Pw + row * 64 + ch * 8 + (lq & 1) * 4) = pk;
      }
    __syncthreads();   // (2) drains Vt[fi]; all waves' K reads done
    if (fi < 7) {
      const unsigned short* kg = Kpad + (size_t)(kimg0 + fi + 1) * (64 * INNER);
#pragma unroll
      for (int j = 0; j < 3; j++) gld16(kg + goK[j], Ks + lo[j]);
    }
    f32x4 pv[2][6] = {{z4, z4, z4, z4, z4, z4}, {z4, z4, z4, z4, z4, z4}};
    __builtin_amdgcn_s_setprio(1);
#pragma unroll
    for (int ks = 0; ks < 2; ks++) {
      int row0 = 0 * 16 + lr, row1 = 1 * 16 + lr;
      int ch0 = ((ks * 4 + lq) ^ (row0 & 7));
      int ch1 = ((ks * 4 + lq) ^ (row1 & 7));
      bf16x8 b0 = *(const bf16x8*)(Pw + row0 * 64 + ch0 * 8);
      bf16x8 b1 = *(const bf16x8*)(Pw + row1 * 64 + ch1 * 8);
#pragma unroll
      for (int et = 0; et < 6; et++) {
        bf16x8 a = *(const bf16x8*)(VtS + et * (16 * 64) + rdV[ks]);
        pv[0][et] = __builtin_amdgcn_mfma_f32_16x16x32_bf16(a, b0, pv[0][et], 0, 0, 0);
        pv[1][et] = __builtin_amdgcn_mfma_f32_16x16x32_bf16(a, b1, pv[1][et], 0, 0, 0);
      }
    }
    __builtin_amdgcn_s_setprio(0);
#pragma unroll
    for (int qt = 0; qt < 2; qt++) {
      f32x2 dp = {0.f, 0.f}, np = {0.f, 0.f};
#pragma unroll
      for (int et = 0; et < 6; et++) {
        f32x2 al0 = __builtin_shufflevector(pv[qt][et], pv[qt][et], 0, 1);
        f32x2 al1 = __builtin_shufflevector(pv[qt][et], pv[qt][et], 2, 3);
        asm("v_pk_fma_f32 %0, %1, %2, %0" : "+v"(dp) : "v"(al0), "v"(rv2[qt][et][0]));
        asm("v_pk_fma_f32 %0, %1, %2, %0" : "+v"(np) : "v"(al0), "v"(al0));
        asm("v_pk_fma_f32 %0, %1, %2, %0" : "+v"(dp) : "v"(al1), "v"(rv2[qt][et][1]));
        asm("v_pk_fma_f32 %0, %1, %2, %0" : "+v"(np) : "v"(al1), "v"(al1));
      }
      float d = dp[0] + dp[1], nn = np[0] + np[1];
      d += __shfl_xor(d, 16, 64);  d += __shfl_xor(d, 32, 64);
      nn += __shfl_xor(nn, 16, 64); nn += __shfl_xor(nn, 32, 64);
      if (lane < 16) {
        float cv = d * __frsqrt_rn(fmaxf(nn, 1e-40f)) * invvn[qt];
        cosbuf[(size_t)(dir * 128 + f) * NSIDE + r0 + w * 32 + qt * 16 + lr] = cv;
      }
    }
  }
}

// ---------------------------------------------------------------------------
// reduce_out: out[bb*128+aa] = (sum_q cos0[bb][aa*49+q] + cos1[aa][bb*49+q])/49
// ---------------------------------------------------------------------------
__global__ __launch_bounds__(256) void reduce_out(const float* __restrict__ cosbuf,
                                                  float* __restrict__ out) {
  const int t = threadIdx.x, lane = t & 63, wv = t >> 6;
  const int pair = blockIdx.x * 4 + wv;
  const int bb = pair >> 7, aa = pair & 127;
  float v = 0.f;
  if (lane < S49) {
    v  = cosbuf[(size_t)bb * NSIDE + aa * S49 + lane];
    v += cosbuf[(size_t)(128 + aa) * NSIDE + bb * S49 + lane];
  }
  for (int m = 1; m < 64; m <<= 1) v += __shfl_xor(v, m, 64);
  if (lane == 0) out[pair] = v * (1.f / 49.f);
}

// ---------------------------------------------------------------------------
extern "C" void kernel_launch(void* const* d_in, const int* in_sizes, int n_in,
                              void* d_out, int out_size, void* d_ws, size_t ws_size,
                              hipStream_t stream) {
  const float* fa  = (const float*)d_in[0];
  const float* fb  = (const float*)d_in[1];
  const float* W1[3] = {(const float*)d_in[2], (const float*)d_in[4], (const float*)d_in[6]};
  const float* W2[3] = {(const float*)d_in[3], (const float*)d_in[5], (const float*)d_in[7]};
  float* out = (float*)d_out;

  unsigned short* p = (unsigned short*)d_ws;
  unsigned short* Xbf = p;                 p += (size_t)MROWS * CDIM;      // 19.3 MB
  unsigned short* W1T = p;                 p += (size_t)3 * CDIM * CDIM;   // 3.5 MB
  unsigned short* W2T = p;                 p += (size_t)3 * INNER * CDIM;  // 0.44 MB
  unsigned short* QKV = p;                 p += (size_t)3 * MROWS * INNER; // 7.2 MB
  unsigned short* Vt  = p;                 p += (size_t)256 * INNER * 64;  // 3.1 MB
  unsigned short* Kpad = p;                p += (size_t)256 * 64 * INNER;  // 3.1 MB (adjacent to Vt!)
  float* vnorm = (float*)p;                p += (size_t)MROWS * 2;         // 50 KB
  float* cosbuf = (float*)p;               p += (size_t)256 * NSIDE * 2;   // 6.4 MB
  float* Opart = (float*)p;                p += (size_t)9 * MROWS * INNER * 2; // 43.4 MB

  prep_all<<<dim3(5112), 256, 0, stream>>>(fa, fb, W1[0], W1[1], W1[2],
                                           W2[0], W2[1], W2[2],
                                           Xbf, W1T, W2T, Vt /* VtKpad span */);
  gemm1f<<<dim3(CDIM / 256, MROWS / 256, 3), 512, 0, stream>>>(Xbf, W1T, W2T, Opart);
  finalize<<<dim3(MROWS / 64, 3), 256, 0, stream>>>(Opart, QKV, Kpad, Vt, vnorm);
  attn13<<<dim3(2 * 784), 256, 0, stream>>>(
      QKV, Kpad, QKV + (size_t)2 * MROWS * INNER, Vt, vnorm, cosbuf);
  reduce_out<<<dim3(4096), 256, 0, stream>>>(cosbuf, out);
}

// Round 13
// 262.970 us; speedup vs baseline: 1.0134x; 1.0134x over previous
//
#include <hip/hip_runtime.h>
#include <hip/hip_bf16.h>
#include <math.h>

typedef __attribute__((ext_vector_type(8))) short bf16x8;
typedef __attribute__((ext_vector_type(4))) float f32x4;
typedef __attribute__((ext_vector_type(2))) float f32x2;

#define MROWS 12544      // (128+128)*49
#define CDIM 768
#define INNER 96
#define S49 49
#define NSIDE 6272       // 128*49 rows per side
#define SCALE 0.10206207261596577f
// SCALE * log2(e): Q prescale so attn can use exp2 directly
#define SCALE_EXP2 ((float)(0.10206207261596577 * 1.4426950408889634))

__device__ __forceinline__ unsigned short f2bf(float f) {
  union { float f; unsigned u; } v; v.f = f;
  unsigned u = v.u;
  return (unsigned short)((u + 0x7fffu + ((u >> 16) & 1u)) >> 16);
}
__device__ __forceinline__ float bf2f(unsigned short h) {
  union { unsigned u; float f; } v; v.u = ((unsigned)h) << 16;
  return v.f;
}
// pack two floats to bf16x2 (round-to-nearest-ish): low=a, high=b
__device__ __forceinline__ unsigned pack_bf16_rn(float a, float b) {
  union { float f; unsigned u; } ua, ub; ua.f = a; ub.f = b;
  return __builtin_amdgcn_perm(ub.u + 0x8000u, ua.u + 0x8000u, 0x07060302u);
}

// async global->LDS, 16B per lane. Dest must be wave-uniform base + lane*16.
__device__ __forceinline__ void gld16(const unsigned short* g, unsigned short* l) {
  __builtin_amdgcn_global_load_lds(
      (const __attribute__((address_space(1))) unsigned int*)(g),
      (__attribute__((address_space(3))) unsigned int*)(l), 16, 0, 0);
}

// ---------------------------------------------------------------------------
// prep_all: one kernel, three phases by block range.
// ---------------------------------------------------------------------------
__global__ __launch_bounds__(256) void prep_all(
    const float* __restrict__ fa, const float* __restrict__ fb,
    const float* __restrict__ w10, const float* __restrict__ w11,
    const float* __restrict__ w12, const float* __restrict__ w20,
    const float* __restrict__ w21, const float* __restrict__ w22,
    unsigned short* __restrict__ X,
    unsigned short* __restrict__ W1T, unsigned short* __restrict__ W2T,
    unsigned short* __restrict__ VtKpad) {
  const int t = threadIdx.x;
  int id = blockIdx.x;
  if (id < 3072) {
    __shared__ float T[64][50];
    const int z = id / 1536; id -= z * 1536;
    const int ct = id % 12, img = id / 12;
    const float* feat = z ? fb : fa;
    const float* src = feat + (size_t)img * (CDIM * S49) + (size_t)ct * 64 * S49;
    for (int idx = t; idx < 64 * S49; idx += 256) {
      int cc = idx / S49, s = idx - cc * S49;
      T[cc][s] = src[cc * S49 + s];
    }
    __syncthreads();
    unsigned short* dst = X + (size_t)(z * 128 + img) * S49 * CDIM + ct * 64;
    for (int idx = t; idx < S49 * 64; idx += 256) {
      int s = idx >> 6, cc = idx & 63;
      dst[(size_t)s * CDIM + cc] = f2bf(T[cc][s]);
    }
  } else if (id < 5016) {
    __shared__ float T[32][33];
    id -= 3072;
    const float* src;
    unsigned short* dst;
    int C, ctile, rtile;
    if (id < 1728) {
      int wdx = id / 576, tid = id - wdx * 576;
      ctile = tid % 24; rtile = tid / 24;
      src = wdx == 0 ? w10 : (wdx == 1 ? w11 : w12);
      dst = W1T + (size_t)wdx * CDIM * CDIM;
      C = CDIM;
    } else {
      id -= 1728;
      int wdx = id / 72, tid = id - wdx * 72;
      ctile = tid % 3; rtile = tid / 3;
      src = wdx == 0 ? w20 : (wdx == 1 ? w21 : w22);
      dst = W2T + (size_t)wdx * INNER * CDIM;
      C = INNER;
    }
    const int c0 = ctile * 32, r0 = rtile * 32;
    for (int idx = t; idx < 1024; idx += 256) {
      int rr = idx >> 5, cc = idx & 31;
      T[rr][cc] = src[(size_t)(r0 + rr) * C + c0 + cc];
    }
    __syncthreads();
    for (int idx = t; idx < 1024; idx += 256) {
      int rr = idx >> 5, cc = idx & 31;
      dst[(size_t)(c0 + rr) * CDIM + r0 + cc] = f2bf(T[cc][rr]);
    }
  } else {
    id -= 5016;
    ushort4* p4 = (ushort4*)VtKpad;
    const ushort4 z = make_ushort4(0, 0, 0, 0);
#pragma unroll
    for (int i = 0; i < 32; i++)
      p4[(size_t)id * 8192 + i * 256 + t] = z;
  }
}

// ---------------------------------------------------------------------------
// gemm1_8p: H[wdx] = relu(X @ W1[wdx]). 256x256 tile, BK=64, 8-phase
// counted-vmcnt schedule (T3+T4). Verified WIN R10 (-19us). Unchanged.
// ---------------------------------------------------------------------------
#define BARR() do { __builtin_amdgcn_sched_barrier(0); \
  __builtin_amdgcn_s_barrier(); __builtin_amdgcn_sched_barrier(0); } while (0)
#define STG(src, dhalf) do { \
  gld16((src), (dhalf) + t8); \
  gld16((src) + 32, (dhalf) + t8 + 4096); } while (0)
#define MFMA_QUAD(QM, QN) do { \
  __builtin_amdgcn_s_setprio(1); \
  _Pragma("unroll") \
  for (int mi = 0; mi < 4; ++mi) { \
    _Pragma("unroll") \
    for (int ni = 0; ni < 2; ++ni) { \
      _Pragma("unroll") \
      for (int ks = 0; ks < 2; ++ks) \
        acc[(QM)*4+mi][(QN)*2+ni] = __builtin_amdgcn_mfma_f32_16x16x32_bf16( \
            Af[mi*2+ks], Bf[((QN)*2+ni)*2+ks], acc[(QM)*4+mi][(QN)*2+ni], \
            0, 0, 0); \
    } \
  } \
  __builtin_amdgcn_s_setprio(0); } while (0)

__global__ __launch_bounds__(512, 2) void gemm1_8p(
    const unsigned short* __restrict__ X,
    const unsigned short* __restrict__ W1T,
    unsigned short* __restrict__ H, int wbase, int hsel) {
  __shared__ __align__(16) unsigned short L[2][4][8192];  // 128 KB
  const int t = threadIdx.x;
  const int lane = t & 63, w = t >> 6;
  const int lr = lane & 15, lq = lane >> 4;
  const int wm2 = w >> 2, wn4 = w & 3;
  // ---- bijective XCD swizzle over the full grid (m204 formula)
  const int gx = gridDim.x, gxy = gx * gridDim.y;
  const int nwg = gxy * gridDim.z;
  const int orig = blockIdx.x + gx * (blockIdx.y + gridDim.y * blockIdx.z);
  const int q8 = nwg >> 3, r8 = nwg & 7;
  const int xcd = orig & 7, rank = orig >> 3;
  const int logical = (xcd < r8 ? xcd * (q8 + 1) : r8 * (q8 + 1) + (xcd - r8) * q8) + rank;
  const int wdx_l = logical / gxy;
  const int rem = logical - wdx_l * gxy;
  const int M0 = (rem / gx) * 256, N0 = (rem % gx) * 256;
  const int wdx = wdx_l + wbase;
  const unsigned short* W1w = W1T + (size_t)wdx * CDIM * CDIM;
  unsigned short* Hw = H + (hsel ? (size_t)wdx * MROWS * CDIM : 0);

  // ---- staging source (per-thread): chunk t -> (r, swizzled col), kb=0/1
  const int rs = t >> 2;
  const int cs = ((t & 3) * 8) ^ (((rs >> 3) & 1) << 4);
  const int soff = rs * CDIM + cs;
  const unsigned short* pA0 = X + (size_t)M0 * CDIM + soff;
  const unsigned short* pA1 = pA0 + (size_t)128 * CDIM;
  const unsigned short* pB0 = W1w + (size_t)N0 * CDIM + soff;
  const unsigned short* pB1 = pB0 + (size_t)128 * CDIM;
  const int t8 = t * 8;

  // ---- ds_read base (same involution as the source preswizzle)
  const int rdbase = lr * 32 + ((lq * 8) ^ (((lr >> 3) & 1) << 4));
  const int bO = (wn4 & 1) * 2048;   // row offset within B half (64 rows)

  const f32x4 z4 = {0.f, 0.f, 0.f, 0.f};
  f32x4 acc[8][4];
#pragma unroll
  for (int i = 0; i < 8; ++i)
#pragma unroll
    for (int j = 0; j < 4; ++j) acc[i][j] = z4;
  bf16x8 Af[8], Bf[8];

  // ---- prologue: tile0 {B0,A0,A1,B1}, tile1 {B0,A0}; land tile0.
  STG(pB0, &L[0][2][0]);
  STG(pA0, &L[0][0][0]);
  STG(pA1, &L[0][1][0]);
  STG(pB1, &L[0][3][0]);
  STG(pB0 + 64, &L[1][2][0]);
  STG(pA0 + 64, &L[1][0][0]);
  asm volatile("s_waitcnt vmcnt(4)" ::: "memory");
  BARR();

  for (int tau = 0; tau < 12; ++tau) {
    const int buf = tau & 1;
    const unsigned short* LA = &L[buf][wm2][0];
    const unsigned short* LB = &L[buf][2 + (wn4 >> 1)][0];
    // ---- phase 0: read A(qm0) + B(qn0); stage A1(tau+1)
#pragma unroll
    for (int mf = 0; mf < 4; ++mf)
#pragma unroll
      for (int ks = 0; ks < 2; ++ks)
        Af[mf * 2 + ks] = *(const bf16x8*)(LA + ks * 4096 + mf * 512 + rdbase);
#pragma unroll
    for (int nf = 0; nf < 2; ++nf)
#pragma unroll
      for (int ks = 0; ks < 2; ++ks)
        Bf[nf * 2 + ks] = *(const bf16x8*)(LB + ks * 4096 + bO + nf * 512 + rdbase);
    if (tau + 1 < 12) STG(pA1 + (tau + 1) * 64, &L[(tau + 1) & 1][1][0]);
    BARR();
    MFMA_QUAD(0, 0);
    BARR();
    // ---- phase 1: read B(qn1); stage B1(tau+1)
#pragma unroll
    for (int nf = 2; nf < 4; ++nf)
#pragma unroll
      for (int ks = 0; ks < 2; ++ks)
        Bf[nf * 2 + ks] = *(const bf16x8*)(LB + ks * 4096 + bO + nf * 512 + rdbase);
    if (tau + 1 < 12) STG(pB1 + (tau + 1) * 64, &L[(tau + 1) & 1][3][0]);
    BARR();
    MFMA_QUAD(0, 1);
    BARR();
    // ---- phase 2: read A(qm1); stage B0(tau+2) (same buf, B-region: done)
#pragma unroll
    for (int mf = 4; mf < 8; ++mf)
#pragma unroll
      for (int ks = 0; ks < 2; ++ks)
        Af[(mf - 4) * 2 + ks] = *(const bf16x8*)(LA + ks * 4096 + mf * 512 + rdbase);
    if (tau + 2 < 12) STG(pB0 + (tau + 2) * 64, &L[buf][2][0]);
    BARR();
    MFMA_QUAD(1, 0);
    BARR();
    // ---- phase 3: stage A0(tau+2); counted vmcnt lands tile tau+1
    if (tau + 2 < 12) STG(pA0 + (tau + 2) * 64, &L[buf][0][0]);
    if (tau < 10) {
      asm volatile("s_waitcnt vmcnt(4)" ::: "memory");
    } else if (tau == 10) {
      asm volatile("s_waitcnt vmcnt(0)" ::: "memory");
    }
    BARR();
    MFMA_QUAD(1, 1);
    BARR();
  }
  // ---- epilogue: m = M0 + wm2*128 + mf*16 + lq*4 + r; n = N0 + wn4*64 + nf*16 + lr
#pragma unroll
  for (int mf = 0; mf < 8; ++mf)
#pragma unroll
    for (int nf = 0; nf < 4; ++nf)
#pragma unroll
      for (int r = 0; r < 4; ++r) {
        int m = M0 + wm2 * 128 + mf * 16 + lq * 4 + r;
        int n = N0 + wn4 * 64 + nf * 16 + lr;
        Hw[(size_t)m * CDIM + n] = f2bf(fmaxf(acc[mf][nf][r], 0.f));
      }
}

// ---------------------------------------------------------------------------
// gemm2b5: O = H[wdx] @ W2[wdx]. Verified R9 (source-preswizzled gld16,
// BK=128, 512 thr / 8 waves, LDS 40960 = 4 blocks/CU). Unchanged.
// ---------------------------------------------------------------------------
__global__ __launch_bounds__(512) void gemm2b5(const unsigned short* __restrict__ H,
                                               const unsigned short* __restrict__ W2T,
                                               unsigned short* __restrict__ QKV,
                                               unsigned short* __restrict__ Kpad,
                                               unsigned short* __restrict__ Vt,
                                               float* __restrict__ vnorm,
                                               int wbase, int hsel) {
  __shared__ __align__(16) unsigned short As[64 * 128];   // 16 KB
  __shared__ __align__(16) unsigned short Bs[96 * 128];   // 24 KB
  const int t = threadIdx.x;
  const int lane = t & 63, w = t >> 6;
  const int lr = lane & 15, lq = lane >> 4;
  const int wm = w & 3, we = w >> 2;      // m quarter (16 rows), e half (48)
  const int m0 = blockIdx.x * 64;
  const int wdx = blockIdx.y + wbase;
  const unsigned short* Hw = H + (hsel ? (size_t)wdx * MROWS * CDIM : 0);
  const unsigned short* W2w = W2T + (size_t)wdx * INNER * CDIM;
  const f32x4 z4 = {0.f, 0.f, 0.f, 0.f};
  f32x4 acc[3] = {z4, z4, z4};

  for (int k0 = 0; k0 < CDIM; k0 += 128) {
    __syncthreads();
#pragma unroll
    for (int j = 0; j < 2; j++) {
      int l = t + j * 512;
      int row = l >> 4, ch = l & 15;
      gld16(Hw + (size_t)(m0 + row) * CDIM + k0 + (ch ^ (row & 7)) * 8, As + l * 8);
    }
#pragma unroll
    for (int j = 0; j < 3; j++) {
      int l = t + j * 512;
      int row = l >> 4, ch = l & 15;
      gld16(W2w + (size_t)row * CDIM + k0 + (ch ^ (row & 7)) * 8, Bs + l * 8);
    }
    __syncthreads();
#pragma unroll
    for (int kk = 0; kk < 4; kk++) {
      int ca = (kk * 4 + lq) ^ (lr & 7);
      bf16x8 a = *(const bf16x8*)(As + (wm * 16 + lr) * 128 + ca * 8);
#pragma unroll
      for (int et = 0; et < 3; et++) {
        bf16x8 b = *(const bf16x8*)(Bs + (we * 48 + et * 16 + lr) * 128 + ca * 8);
        acc[et] = __builtin_amdgcn_mfma_f32_16x16x32_bf16(a, b, acc[et], 0, 0, 0);
      }
    }
  }
  float nsq[4] = {0.f, 0.f, 0.f, 0.f};
#pragma unroll
  for (int et = 0; et < 3; et++)
#pragma unroll
    for (int r = 0; r < 4; r++) {
      int m = m0 + wm * 16 + lq * 4 + r;
      int e = we * 48 + et * 16 + lr;
      float v = acc[et][r];
      int img = m / 49, s = m - img * 49;
      if (wdx == 0) {
        QKV[(size_t)m * INNER + e] = f2bf(v * SCALE_EXP2);
      } else if (wdx == 1) {
        Kpad[(size_t)(img * 64 + s) * INNER + e] = f2bf(v);
      } else {
        QKV[(size_t)(2 * MROWS + m) * INNER + e] = f2bf(v);
        Vt[(size_t)img * (INNER * 64) + e * 64 + s] = f2bf(v);
        nsq[r] += v * v;
      }
    }
  if (wdx == 2) {
    __syncthreads();
    float (*nsqp)[64] = (float (*)[64])As;
#pragma unroll
    for (int r = 0; r < 4; r++) {
      float p = nsq[r];
      p += __shfl_xor(p, 1, 16);
      p += __shfl_xor(p, 2, 16);
      p += __shfl_xor(p, 4, 16);
      p += __shfl_xor(p, 8, 16);
      if (lr == 0) nsqp[we][wm * 16 + lq * 4 + r] = p;
    }
    __syncthreads();
    if (t < 64) vnorm[m0 + t] = sqrtf(nsqp[0][t] + nsqp[1][t]);
  }
}

// ---------------------------------------------------------------------------
// attn14: attn13 (verified ~90us) with fg 16->8: 784 blocks x 16 fi.
// R12 insight: OccupancyPercent ~17% across ALL capacity variants -> attn is
// per-block latency-bound, not capacity-bound. Halving block count amortizes
// the serial per-block prologue (Q/rv/vnorm loads, index setup) over 2x the
// fi and removes the 544-block second-round tail (784 <= 1024 co-resident).
// Structure (fg*16+fi, 16 iterations) is R0-attn9-validated.
// ---------------------------------------------------------------------------
__global__ __launch_bounds__(256) void attn14(const unsigned short* __restrict__ Qp,
                                              const unsigned short* __restrict__ Kpad,
                                              const unsigned short* __restrict__ V,
                                              const unsigned short* __restrict__ Vt,
                                              const float* __restrict__ vnorm,
                                              float* __restrict__ cosbuf) {
  __shared__ __align__(16) unsigned short Ks[64 * INNER];      // 12 KB
  __shared__ __align__(16) unsigned short VtS[INNER * 64];     // 12 KB
  __shared__ __align__(16) unsigned short Ps[4][32 * 64];      // 16 KB

  const int t = threadIdx.x;
  const int lane = t & 63, w = t >> 6;
  const int lr = lane & 15, lq = lane >> 4;
  const f32x4 z4 = {0.f, 0.f, 0.f, 0.f};

  int bx = blockIdx.x;
  const int dir = bx / 392; bx -= dir * 392;     // 392 = 49 chunks * 8 fgroups
  const int chunk = bx >> 3, fg = bx & 7;
  const int r0 = chunk * 128;
  const int qbase = dir * NSIDE;

  int goK[3], goV[3], lo[3];
#pragma unroll
  for (int j = 0; j < 3; j++) {
    int l = (w * 3 + j) * 64 + lane;
    lo[j] = l * 8;
    int rK = l / 12, scK = l - rK * 12;
    int ccK = scK - ((rK >> 1) & 7); if (ccK < 0) ccK += 12;
    goK[j] = rK * INNER + ccK * 8;
    int rV = l >> 3, scV = l & 7;
    int ccV = (scV - (rV & 7)) & 7;
    goV[j] = rV * 64 + ccV * 8;
  }
  int rdK[3], rdV[2];
#pragma unroll
  for (int ks = 0; ks < 3; ks++) {
    int sc = (ks * 4 + lq + ((lr >> 1) & 7)) % 12;
    rdK[ks] = lr * INNER + sc * 8;
  }
#pragma unroll
  for (int ks = 0; ks < 2; ks++) {
    int sc = (ks * 4 + lq + (lr & 7)) & 7;
    rdV[ks] = lr * 64 + sc * 8;
  }

  bf16x8 qf[2][3];
#pragma unroll
  for (int qt = 0; qt < 2; qt++) {
    const int qrow = qbase + r0 + w * 32 + qt * 16 + lr;
#pragma unroll
    for (int ks = 0; ks < 3; ks++)
      qf[qt][ks] = *(const bf16x8*)(Qp + (size_t)qrow * INNER + ks * 32 + lq * 8);
  }
  f32x2 rv2[2][6][2];
  float invvn[2];
#pragma unroll
  for (int qt = 0; qt < 2; qt++) {
    const int qrow = qbase + r0 + w * 32 + qt * 16 + lr;
    invvn[qt] = 1.f / fmaxf(vnorm[qrow], 1e-8f);
#pragma unroll
    for (int et = 0; et < 6; et++) {
      ushort4 u = *(const ushort4*)(V + (size_t)qrow * INNER + et * 16 + lq * 4);
      rv2[qt][et][0] = (f32x2){bf2f(u.x), bf2f(u.y)};
      rv2[qt][et][1] = (f32x2){bf2f(u.z), bf2f(u.w)};
    }
  }

  unsigned short* Pw = &Ps[w][0];
  const int kimg0 = (dir == 0 ? 128 : 0) + fg * 16;
  {
    const unsigned short* kg = Kpad + (size_t)kimg0 * (64 * INNER);
#pragma unroll
    for (int j = 0; j < 3; j++) gld16(kg + goK[j], Ks + lo[j]);
  }
  for (int fi = 0; fi < 16; fi++) {
    const int f = fg * 16 + fi;
    __syncthreads();   // (1) drains K[fi]; prev PV done by all waves
    {
      const unsigned short* vg = Vt + (size_t)(kimg0 + fi) * (INNER * 64);
#pragma unroll
      for (int j = 0; j < 3; j++) gld16(vg + goV[j], VtS + lo[j]);
    }
    f32x4 s4[2][4] = {{z4, z4, z4, z4}, {z4, z4, z4, z4}};
    __builtin_amdgcn_s_setprio(1);
#pragma unroll
    for (int ks = 0; ks < 3; ks++) {
#pragma unroll
      for (int kt = 0; kt < 4; kt++) {
        bf16x8 a = *(const bf16x8*)(Ks + kt * (16 * INNER) + rdK[ks]);
        s4[0][kt] = __builtin_amdgcn_mfma_f32_16x16x32_bf16(a, qf[0][ks], s4[0][kt], 0, 0, 0);
        s4[1][kt] = __builtin_amdgcn_mfma_f32_16x16x32_bf16(a, qf[1][ks], s4[1][kt], 0, 0, 0);
      }
    }
    __builtin_amdgcn_s_setprio(0);
#pragma unroll
    for (int qt = 0; qt < 2; qt++)
#pragma unroll
      for (int kt = 0; kt < 4; kt++) {
        float e0 = __builtin_exp2f(s4[qt][kt][0]);
        float e1 = __builtin_exp2f(s4[qt][kt][1]);
        float e2 = __builtin_exp2f(s4[qt][kt][2]);
        float e3 = __builtin_exp2f(s4[qt][kt][3]);
        unsigned lopk, hipk;
        asm("v_cvt_pk_bf16_f32 %0, %1, %2" : "=v"(lopk) : "v"(e0), "v"(e1));
        asm("v_cvt_pk_bf16_f32 %0, %1, %2" : "=v"(hipk) : "v"(e2), "v"(e3));
        uint2 pk = make_uint2(lopk, hipk);
        int row = qt * 16 + lr;
        int ch = (2 * kt + (lq >> 1)) ^ (row & 7);
        *(uint2*)(Pw + row * 64 + ch * 8 + (lq & 1) * 4) = pk;
      }
    __syncthreads();   // (2) drains Vt[fi]; all waves' K reads done
    if (fi < 15) {
      const unsigned short* kg = Kpad + (size_t)(kimg0 + fi + 1) * (64 * INNER);
#pragma unroll
      for (int j = 0; j < 3; j++) gld16(kg + goK[j], Ks + lo[j]);
    }
    f32x4 pv[2][6] = {{z4, z4, z4, z4, z4, z4}, {z4, z4, z4, z4, z4, z4}};
    __builtin_amdgcn_s_setprio(1);
#pragma unroll
    for (int ks = 0; ks < 2; ks++) {
      int row0 = 0 * 16 + lr, row1 = 1 * 16 + lr;
      int ch0 = ((ks * 4 + lq) ^ (row0 & 7));
      int ch1 = ((ks * 4 + lq) ^ (row1 & 7));
      bf16x8 b0 = *(const bf16x8*)(Pw + row0 * 64 + ch0 * 8);
      bf16x8 b1 = *(const bf16x8*)(Pw + row1 * 64 + ch1 * 8);
#pragma unroll
      for (int et = 0; et < 6; et++) {
        bf16x8 a = *(const bf16x8*)(VtS + et * (16 * 64) + rdV[ks]);
        pv[0][et] = __builtin_amdgcn_mfma_f32_16x16x32_bf16(a, b0, pv[0][et], 0, 0, 0);
        pv[1][et] = __builtin_amdgcn_mfma_f32_16x16x32_bf16(a, b1, pv[1][et], 0, 0, 0);
      }
    }
    __builtin_amdgcn_s_setprio(0);
#pragma unroll
    for (int qt = 0; qt < 2; qt++) {
      f32x2 dp = {0.f, 0.f}, np = {0.f, 0.f};
#pragma unroll
      for (int et = 0; et < 6; et++) {
        f32x2 al0 = __builtin_shufflevector(pv[qt][et], pv[qt][et], 0, 1);
        f32x2 al1 = __builtin_shufflevector(pv[qt][et], pv[qt][et], 2, 3);
        asm("v_pk_fma_f32 %0, %1, %2, %0" : "+v"(dp) : "v"(al0), "v"(rv2[qt][et][0]));
        asm("v_pk_fma_f32 %0, %1, %2, %0" : "+v"(np) : "v"(al0), "v"(al0));
        asm("v_pk_fma_f32 %0, %1, %2, %0" : "+v"(dp) : "v"(al1), "v"(rv2[qt][et][1]));
        asm("v_pk_fma_f32 %0, %1, %2, %0" : "+v"(np) : "v"(al1), "v"(al1));
      }
      float d = dp[0] + dp[1], nn = np[0] + np[1];
      d += __shfl_xor(d, 16, 64);  d += __shfl_xor(d, 32, 64);
      nn += __shfl_xor(nn, 16, 64); nn += __shfl_xor(nn, 32, 64);
      if (lane < 16) {
        float cv = d * __frsqrt_rn(fmaxf(nn, 1e-40f)) * invvn[qt];
        cosbuf[(size_t)(dir * 128 + f) * NSIDE + r0 + w * 32 + qt * 16 + lr] = cv;
      }
    }
  }
}

// ---------------------------------------------------------------------------
// reduce_out: out[bb*128+aa] = (sum_q cos0[bb][aa*49+q] + cos1[aa][bb*49+q])/49
// ---------------------------------------------------------------------------
__global__ __launch_bounds__(256) void reduce_out(const float* __restrict__ cosbuf,
                                                  float* __restrict__ out) {
  const int t = threadIdx.x, lane = t & 63, wv = t >> 6;
  const int pair = blockIdx.x * 4 + wv;
  const int bb = pair >> 7, aa = pair & 127;
  float v = 0.f;
  if (lane < S49) {
    v  = cosbuf[(size_t)bb * NSIDE + aa * S49 + lane];
    v += cosbuf[(size_t)(128 + aa) * NSIDE + bb * S49 + lane];
  }
  for (int m = 1; m < 64; m <<= 1) v += __shfl_xor(v, m, 64);
  if (lane == 0) out[pair] = v * (1.f / 49.f);
}

// ---------------------------------------------------------------------------
extern "C" void kernel_launch(void* const* d_in, const int* in_sizes, int n_in,
                              void* d_out, int out_size, void* d_ws, size_t ws_size,
                              hipStream_t stream) {
  const float* fa  = (const float*)d_in[0];
  const float* fb  = (const float*)d_in[1];
  const float* W1[3] = {(const float*)d_in[2], (const float*)d_in[4], (const float*)d_in[6]};
  const float* W2[3] = {(const float*)d_in[3], (const float*)d_in[5], (const float*)d_in[7]};
  float* out = (float*)d_out;

  unsigned short* p = (unsigned short*)d_ws;
  unsigned short* Xbf = p;                 p += (size_t)MROWS * CDIM;      // 19.3 MB
  unsigned short* W1T = p;                 p += (size_t)3 * CDIM * CDIM;   // 3.5 MB
  unsigned short* W2T = p;                 p += (size_t)3 * INNER * CDIM;  // 0.44 MB
  unsigned short* QKV = p;                 p += (size_t)3 * MROWS * INNER; // 7.2 MB
  unsigned short* Vt  = p;                 p += (size_t)256 * INNER * 64;  // 3.1 MB
  unsigned short* Kpad = p;                p += (size_t)256 * 64 * INNER;  // 3.1 MB (adjacent to Vt!)
  float* vnorm = (float*)p;                p += (size_t)MROWS * 2;         // 50 KB
  float* cosbuf = (float*)p;               p += (size_t)256 * NSIDE * 2;   // 6.4 MB
  unsigned short* H = p;                   p += (size_t)3 * MROWS * CDIM;  // 57.8 MB (batched)
  const size_t need_batched = (size_t)(p - (unsigned short*)d_ws) * 2;
  const int batched = ws_size >= need_batched;

  prep_all<<<dim3(5112), 256, 0, stream>>>(fa, fb, W1[0], W1[1], W1[2],
                                           W2[0], W2[1], W2[2],
                                           Xbf, W1T, W2T, Vt /* VtKpad span */);
  if (batched) {
    gemm1_8p<<<dim3(CDIM / 256, MROWS / 256, 3), 512, 0, stream>>>(Xbf, W1T, H, 0, 1);
    gemm2b5<<<dim3(MROWS / 64, 3), 512, 0, stream>>>(H, W2T, QKV, Kpad, Vt, vnorm, 0, 1);
  } else {
    for (int wdx = 0; wdx < 3; wdx++) {
      gemm1_8p<<<dim3(CDIM / 256, MROWS / 256, 1), 512, 0, stream>>>(Xbf, W1T, H, wdx, 0);
      gemm2b5<<<dim3(MROWS / 64, 1), 512, 0, stream>>>(H, W2T, QKV, Kpad, Vt, vnorm, wdx, 0);
    }
  }
  attn14<<<dim3(2 * 392), 256, 0, stream>>>(
      QKV, Kpad, QKV + (size_t)2 * MROWS * INNER, Vt, vnorm, cosbuf);
  reduce_out<<<dim3(4096), 256, 0, stream>>>(cosbuf, out);
}

// Round 14
// 255.706 us; speedup vs baseline: 1.0422x; 1.0284x over previous
//
#include <hip/hip_runtime.h>
#include <hip/hip_bf16.h>
#include <math.h>

typedef __attribute__((ext_vector_type(8))) short bf16x8;
typedef __attribute__((ext_vector_type(4))) float f32x4;
typedef __attribute__((ext_vector_type(2))) float f32x2;

#define MROWS 12544      // (128+128)*49
#define CDIM 768
#define INNER 96
#define S49 49
#define NSIDE 6272       // 128*49 rows per side
#define SCALE 0.10206207261596577f
// SCALE * log2(e): Q prescale so attn can use exp2 directly
#define SCALE_EXP2 ((float)(0.10206207261596577 * 1.4426950408889634))

__device__ __forceinline__ unsigned short f2bf(float f) {
  union { float f; unsigned u; } v; v.f = f;
  unsigned u = v.u;
  return (unsigned short)((u + 0x7fffu + ((u >> 16) & 1u)) >> 16);
}
__device__ __forceinline__ float bf2f(unsigned short h) {
  union { unsigned u; float f; } v; v.u = ((unsigned)h) << 16;
  return v.f;
}
// pack two floats to bf16x2 (round-to-nearest-ish): low=a, high=b
__device__ __forceinline__ unsigned pack_bf16_rn(float a, float b) {
  union { float f; unsigned u; } ua, ub; ua.f = a; ub.f = b;
  return __builtin_amdgcn_perm(ub.u + 0x8000u, ua.u + 0x8000u, 0x07060302u);
}

// async global->LDS, 16B per lane. Dest must be wave-uniform base + lane*16.
__device__ __forceinline__ void gld16(const unsigned short* g, unsigned short* l) {
  __builtin_amdgcn_global_load_lds(
      (const __attribute__((address_space(1))) unsigned int*)(g),
      (__attribute__((address_space(3))) unsigned int*)(l), 16, 0, 0);
}

// ---------------------------------------------------------------------------
// prep_all: one kernel, three phases by block range. R13 rider: X / W1T / W2T
// stores packed to bf16x2 (unsigned) — doubles store width vs scalar ushort
// (G13 applies to stores too). Same pack_bf16_rn rounding used for H/P.
// ---------------------------------------------------------------------------
__global__ __launch_bounds__(256) void prep_all(
    const float* __restrict__ fa, const float* __restrict__ fb,
    const float* __restrict__ w10, const float* __restrict__ w11,
    const float* __restrict__ w12, const float* __restrict__ w20,
    const float* __restrict__ w21, const float* __restrict__ w22,
    unsigned short* __restrict__ X,
    unsigned short* __restrict__ W1T, unsigned short* __restrict__ W2T,
    unsigned short* __restrict__ VtKpad) {
  const int t = threadIdx.x;
  int id = blockIdx.x;
  if (id < 3072) {
    __shared__ float T[64][50];
    const int z = id / 1536; id -= z * 1536;
    const int ct = id % 12, img = id / 12;
    const float* feat = z ? fb : fa;
    const float* src = feat + (size_t)img * (CDIM * S49) + (size_t)ct * 64 * S49;
    for (int idx = t; idx < 64 * S49; idx += 256) {
      int cc = idx / S49, s = idx - cc * S49;
      T[cc][s] = src[cc * S49 + s];
    }
    __syncthreads();
    unsigned short* dst = X + (size_t)(z * 128 + img) * S49 * CDIM + ct * 64;
    for (int idx = t; idx < S49 * 32; idx += 256) {
      int s = idx >> 5, c2 = idx & 31;
      *(unsigned*)(dst + (size_t)s * CDIM + c2 * 2) =
          pack_bf16_rn(T[c2 * 2][s], T[c2 * 2 + 1][s]);
    }
  } else if (id < 5016) {
    __shared__ float T[32][33];
    id -= 3072;
    const float* src;
    unsigned short* dst;
    int C, ctile, rtile;
    if (id < 1728) {
      int wdx = id / 576, tid = id - wdx * 576;
      ctile = tid % 24; rtile = tid / 24;
      src = wdx == 0 ? w10 : (wdx == 1 ? w11 : w12);
      dst = W1T + (size_t)wdx * CDIM * CDIM;
      C = CDIM;
    } else {
      id -= 1728;
      int wdx = id / 72, tid = id - wdx * 72;
      ctile = tid % 3; rtile = tid / 3;
      src = wdx == 0 ? w20 : (wdx == 1 ? w21 : w22);
      dst = W2T + (size_t)wdx * INNER * CDIM;
      C = INNER;
    }
    const int c0 = ctile * 32, r0 = rtile * 32;
    for (int idx = t; idx < 1024; idx += 256) {
      int rr = idx >> 5, cc = idx & 31;
      T[rr][cc] = src[(size_t)(r0 + rr) * C + c0 + cc];
    }
    __syncthreads();
    for (int idx = t; idx < 512; idx += 256) {
      int rr = idx >> 4, c2 = idx & 15;
      *(unsigned*)(dst + (size_t)(c0 + rr) * CDIM + r0 + c2 * 2) =
          pack_bf16_rn(T[c2 * 2][rr], T[c2 * 2 + 1][rr]);
    }
  } else {
    id -= 5016;
    ushort4* p4 = (ushort4*)VtKpad;
    const ushort4 z = make_ushort4(0, 0, 0, 0);
#pragma unroll
    for (int i = 0; i < 32; i++)
      p4[(size_t)id * 8192 + i * 256 + t] = z;
  }
}

// ---------------------------------------------------------------------------
// gemm1_8p: H[wdx] = relu(X @ W1[wdx]). 256x256 tile, BK=64, 8-phase
// counted-vmcnt schedule (T3+T4). Verified WIN R10 (-19us). Unchanged.
// ---------------------------------------------------------------------------
#define BARR() do { __builtin_amdgcn_sched_barrier(0); \
  __builtin_amdgcn_s_barrier(); __builtin_amdgcn_sched_barrier(0); } while (0)
#define STG(src, dhalf) do { \
  gld16((src), (dhalf) + t8); \
  gld16((src) + 32, (dhalf) + t8 + 4096); } while (0)
#define MFMA_QUAD(QM, QN) do { \
  __builtin_amdgcn_s_setprio(1); \
  _Pragma("unroll") \
  for (int mi = 0; mi < 4; ++mi) { \
    _Pragma("unroll") \
    for (int ni = 0; ni < 2; ++ni) { \
      _Pragma("unroll") \
      for (int ks = 0; ks < 2; ++ks) \
        acc[(QM)*4+mi][(QN)*2+ni] = __builtin_amdgcn_mfma_f32_16x16x32_bf16( \
            Af[mi*2+ks], Bf[((QN)*2+ni)*2+ks], acc[(QM)*4+mi][(QN)*2+ni], \
            0, 0, 0); \
    } \
  } \
  __builtin_amdgcn_s_setprio(0); } while (0)

__global__ __launch_bounds__(512, 2) void gemm1_8p(
    const unsigned short* __restrict__ X,
    const unsigned short* __restrict__ W1T,
    unsigned short* __restrict__ H, int wbase, int hsel) {
  __shared__ __align__(16) unsigned short L[2][4][8192];  // 128 KB
  const int t = threadIdx.x;
  const int lane = t & 63, w = t >> 6;
  const int lr = lane & 15, lq = lane >> 4;
  const int wm2 = w >> 2, wn4 = w & 3;
  // ---- bijective XCD swizzle over the full grid (m204 formula)
  const int gx = gridDim.x, gxy = gx * gridDim.y;
  const int nwg = gxy * gridDim.z;
  const int orig = blockIdx.x + gx * (blockIdx.y + gridDim.y * blockIdx.z);
  const int q8 = nwg >> 3, r8 = nwg & 7;
  const int xcd = orig & 7, rank = orig >> 3;
  const int logical = (xcd < r8 ? xcd * (q8 + 1) : r8 * (q8 + 1) + (xcd - r8) * q8) + rank;
  const int wdx_l = logical / gxy;
  const int rem = logical - wdx_l * gxy;
  const int M0 = (rem / gx) * 256, N0 = (rem % gx) * 256;
  const int wdx = wdx_l + wbase;
  const unsigned short* W1w = W1T + (size_t)wdx * CDIM * CDIM;
  unsigned short* Hw = H + (hsel ? (size_t)wdx * MROWS * CDIM : 0);

  // ---- staging source (per-thread): chunk t -> (r, swizzled col), kb=0/1
  const int rs = t >> 2;
  const int cs = ((t & 3) * 8) ^ (((rs >> 3) & 1) << 4);
  const int soff = rs * CDIM + cs;
  const unsigned short* pA0 = X + (size_t)M0 * CDIM + soff;
  const unsigned short* pA1 = pA0 + (size_t)128 * CDIM;
  const unsigned short* pB0 = W1w + (size_t)N0 * CDIM + soff;
  const unsigned short* pB1 = pB0 + (size_t)128 * CDIM;
  const int t8 = t * 8;

  // ---- ds_read base (same involution as the source preswizzle)
  const int rdbase = lr * 32 + ((lq * 8) ^ (((lr >> 3) & 1) << 4));
  const int bO = (wn4 & 1) * 2048;   // row offset within B half (64 rows)

  const f32x4 z4 = {0.f, 0.f, 0.f, 0.f};
  f32x4 acc[8][4];
#pragma unroll
  for (int i = 0; i < 8; ++i)
#pragma unroll
    for (int j = 0; j < 4; ++j) acc[i][j] = z4;
  bf16x8 Af[8], Bf[8];

  // ---- prologue: tile0 {B0,A0,A1,B1}, tile1 {B0,A0}; land tile0.
  STG(pB0, &L[0][2][0]);
  STG(pA0, &L[0][0][0]);
  STG(pA1, &L[0][1][0]);
  STG(pB1, &L[0][3][0]);
  STG(pB0 + 64, &L[1][2][0]);
  STG(pA0 + 64, &L[1][0][0]);
  asm volatile("s_waitcnt vmcnt(4)" ::: "memory");
  BARR();

  for (int tau = 0; tau < 12; ++tau) {
    const int buf = tau & 1;
    const unsigned short* LA = &L[buf][wm2][0];
    const unsigned short* LB = &L[buf][2 + (wn4 >> 1)][0];
    // ---- phase 0: read A(qm0) + B(qn0); stage A1(tau+1)
#pragma unroll
    for (int mf = 0; mf < 4; ++mf)
#pragma unroll
      for (int ks = 0; ks < 2; ++ks)
        Af[mf * 2 + ks] = *(const bf16x8*)(LA + ks * 4096 + mf * 512 + rdbase);
#pragma unroll
    for (int nf = 0; nf < 2; ++nf)
#pragma unroll
      for (int ks = 0; ks < 2; ++ks)
        Bf[nf * 2 + ks] = *(const bf16x8*)(LB + ks * 4096 + bO + nf * 512 + rdbase);
    if (tau + 1 < 12) STG(pA1 + (tau + 1) * 64, &L[(tau + 1) & 1][1][0]);
    BARR();
    MFMA_QUAD(0, 0);
    BARR();
    // ---- phase 1: read B(qn1); stage B1(tau+1)
#pragma unroll
    for (int nf = 2; nf < 4; ++nf)
#pragma unroll
      for (int ks = 0; ks < 2; ++ks)
        Bf[nf * 2 + ks] = *(const bf16x8*)(LB + ks * 4096 + bO + nf * 512 + rdbase);
    if (tau + 1 < 12) STG(pB1 + (tau + 1) * 64, &L[(tau + 1) & 1][3][0]);
    BARR();
    MFMA_QUAD(0, 1);
    BARR();
    // ---- phase 2: read A(qm1); stage B0(tau+2) (same buf, B-region: done)
#pragma unroll
    for (int mf = 4; mf < 8; ++mf)
#pragma unroll
      for (int ks = 0; ks < 2; ++ks)
        Af[(mf - 4) * 2 + ks] = *(const bf16x8*)(LA + ks * 4096 + mf * 512 + rdbase);
    if (tau + 2 < 12) STG(pB0 + (tau + 2) * 64, &L[buf][2][0]);
    BARR();
    MFMA_QUAD(1, 0);
    BARR();
    // ---- phase 3: stage A0(tau+2); counted vmcnt lands tile tau+1
    if (tau + 2 < 12) STG(pA0 + (tau + 2) * 64, &L[buf][0][0]);
    if (tau < 10) {
      asm volatile("s_waitcnt vmcnt(4)" ::: "memory");
    } else if (tau == 10) {
      asm volatile("s_waitcnt vmcnt(0)" ::: "memory");
    }
    BARR();
    MFMA_QUAD(1, 1);
    BARR();
  }
  // ---- epilogue: m = M0 + wm2*128 + mf*16 + lq*4 + r; n = N0 + wn4*64 + nf*16 + lr
#pragma unroll
  for (int mf = 0; mf < 8; ++mf)
#pragma unroll
    for (int nf = 0; nf < 4; ++nf)
#pragma unroll
      for (int r = 0; r < 4; ++r) {
        int m = M0 + wm2 * 128 + mf * 16 + lq * 4 + r;
        int n = N0 + wn4 * 64 + nf * 16 + lr;
        Hw[(size_t)m * CDIM + n] = f2bf(fmaxf(acc[mf][nf][r], 0.f));
      }
}

// ---------------------------------------------------------------------------
// gemm2b5: O = H[wdx] @ W2[wdx]. Verified R9 (source-preswizzled gld16,
// BK=128, 512 thr / 8 waves, LDS 40960 = 4 blocks/CU). Unchanged.
// ---------------------------------------------------------------------------
__global__ __launch_bounds__(512) void gemm2b5(const unsigned short* __restrict__ H,
                                               const unsigned short* __restrict__ W2T,
                                               unsigned short* __restrict__ QKV,
                                               unsigned short* __restrict__ Kpad,
                                               unsigned short* __restrict__ Vt,
                                               float* __restrict__ vnorm,
                                               int wbase, int hsel) {
  __shared__ __align__(16) unsigned short As[64 * 128];   // 16 KB
  __shared__ __align__(16) unsigned short Bs[96 * 128];   // 24 KB
  const int t = threadIdx.x;
  const int lane = t & 63, w = t >> 6;
  const int lr = lane & 15, lq = lane >> 4;
  const int wm = w & 3, we = w >> 2;      // m quarter (16 rows), e half (48)
  const int m0 = blockIdx.x * 64;
  const int wdx = blockIdx.y + wbase;
  const unsigned short* Hw = H + (hsel ? (size_t)wdx * MROWS * CDIM : 0);
  const unsigned short* W2w = W2T + (size_t)wdx * INNER * CDIM;
  const f32x4 z4 = {0.f, 0.f, 0.f, 0.f};
  f32x4 acc[3] = {z4, z4, z4};

  for (int k0 = 0; k0 < CDIM; k0 += 128) {
    __syncthreads();
#pragma unroll
    for (int j = 0; j < 2; j++) {
      int l = t + j * 512;
      int row = l >> 4, ch = l & 15;
      gld16(Hw + (size_t)(m0 + row) * CDIM + k0 + (ch ^ (row & 7)) * 8, As + l * 8);
    }
#pragma unroll
    for (int j = 0; j < 3; j++) {
      int l = t + j * 512;
      int row = l >> 4, ch = l & 15;
      gld16(W2w + (size_t)row * CDIM + k0 + (ch ^ (row & 7)) * 8, Bs + l * 8);
    }
    __syncthreads();
#pragma unroll
    for (int kk = 0; kk < 4; kk++) {
      int ca = (kk * 4 + lq) ^ (lr & 7);
      bf16x8 a = *(const bf16x8*)(As + (wm * 16 + lr) * 128 + ca * 8);
#pragma unroll
      for (int et = 0; et < 3; et++) {
        bf16x8 b = *(const bf16x8*)(Bs + (we * 48 + et * 16 + lr) * 128 + ca * 8);
        acc[et] = __builtin_amdgcn_mfma_f32_16x16x32_bf16(a, b, acc[et], 0, 0, 0);
      }
    }
  }
  float nsq[4] = {0.f, 0.f, 0.f, 0.f};
#pragma unroll
  for (int et = 0; et < 3; et++)
#pragma unroll
    for (int r = 0; r < 4; r++) {
      int m = m0 + wm * 16 + lq * 4 + r;
      int e = we * 48 + et * 16 + lr;
      float v = acc[et][r];
      int img = m / 49, s = m - img * 49;
      if (wdx == 0) {
        QKV[(size_t)m * INNER + e] = f2bf(v * SCALE_EXP2);
      } else if (wdx == 1) {
        Kpad[(size_t)(img * 64 + s) * INNER + e] = f2bf(v);
      } else {
        QKV[(size_t)(2 * MROWS + m) * INNER + e] = f2bf(v);
        Vt[(size_t)img * (INNER * 64) + e * 64 + s] = f2bf(v);
        nsq[r] += v * v;
      }
    }
  if (wdx == 2) {
    __syncthreads();
    float (*nsqp)[64] = (float (*)[64])As;
#pragma unroll
    for (int r = 0; r < 4; r++) {
      float p = nsq[r];
      p += __shfl_xor(p, 1, 16);
      p += __shfl_xor(p, 2, 16);
      p += __shfl_xor(p, 4, 16);
      p += __shfl_xor(p, 8, 16);
      if (lr == 0) nsqp[we][wm * 16 + lq * 4 + r] = p;
    }
    __syncthreads();
    if (t < 64) vnorm[m0 + t] = sqrtf(nsqp[0][t] + nsqp[1][t]);
  }
}

// ---------------------------------------------------------------------------
// attn13 (verified 90.3us R11, confirmed best config R13: fg=16 / 1568
// blocks keeps 4 blocks/CU resident; fg=8 regressed to 3/CU): K single-
// buffered, Vt async-staged, 2 barriers/fi, LDS 40960, setprio on MFMA,
// cvt_pk P-pack + pk_fma cosine epilogue.
// ---------------------------------------------------------------------------
__global__ __launch_bounds__(256) void attn13(const unsigned short* __restrict__ Qp,
                                              const unsigned short* __restrict__ Kpad,
                                              const unsigned short* __restrict__ V,
                                              const unsigned short* __restrict__ Vt,
                                              const float* __restrict__ vnorm,
                                              float* __restrict__ cosbuf) {
  __shared__ __align__(16) unsigned short Ks[64 * INNER];      // 12 KB
  __shared__ __align__(16) unsigned short VtS[INNER * 64];     // 12 KB
  __shared__ __align__(16) unsigned short Ps[4][32 * 64];      // 16 KB

  const int t = threadIdx.x;
  const int lane = t & 63, w = t >> 6;
  const int lr = lane & 15, lq = lane >> 4;
  const f32x4 z4 = {0.f, 0.f, 0.f, 0.f};

  int bx = blockIdx.x;
  const int dir = bx / 784; bx -= dir * 784;     // 784 = 49 chunks * 16 fgroups
  const int chunk = bx >> 4, fg = bx & 15;
  const int r0 = chunk * 128;
  const int qbase = dir * NSIDE;

  int goK[3], goV[3], lo[3];
#pragma unroll
  for (int j = 0; j < 3; j++) {
    int l = (w * 3 + j) * 64 + lane;
    lo[j] = l * 8;
    int rK = l / 12, scK = l - rK * 12;
    int ccK = scK - ((rK >> 1) & 7); if (ccK < 0) ccK += 12;
    goK[j] = rK * INNER + ccK * 8;
    int rV = l >> 3, scV = l & 7;
    int ccV = (scV - (rV & 7)) & 7;
    goV[j] = rV * 64 + ccV * 8;
  }
  int rdK[3], rdV[2];
#pragma unroll
  for (int ks = 0; ks < 3; ks++) {
    int sc = (ks * 4 + lq + ((lr >> 1) & 7)) % 12;
    rdK[ks] = lr * INNER + sc * 8;
  }
#pragma unroll
  for (int ks = 0; ks < 2; ks++) {
    int sc = (ks * 4 + lq + (lr & 7)) & 7;
    rdV[ks] = lr * 64 + sc * 8;
  }

  bf16x8 qf[2][3];
#pragma unroll
  for (int qt = 0; qt < 2; qt++) {
    const int qrow = qbase + r0 + w * 32 + qt * 16 + lr;
#pragma unroll
    for (int ks = 0; ks < 3; ks++)
      qf[qt][ks] = *(const bf16x8*)(Qp + (size_t)qrow * INNER + ks * 32 + lq * 8);
  }
  f32x2 rv2[2][6][2];
  float invvn[2];
#pragma unroll
  for (int qt = 0; qt < 2; qt++) {
    const int qrow = qbase + r0 + w * 32 + qt * 16 + lr;
    invvn[qt] = 1.f / fmaxf(vnorm[qrow], 1e-8f);
#pragma unroll
    for (int et = 0; et < 6; et++) {
      ushort4 u = *(const ushort4*)(V + (size_t)qrow * INNER + et * 16 + lq * 4);
      rv2[qt][et][0] = (f32x2){bf2f(u.x), bf2f(u.y)};
      rv2[qt][et][1] = (f32x2){bf2f(u.z), bf2f(u.w)};
    }
  }

  unsigned short* Pw = &Ps[w][0];
  const int kimg0 = (dir == 0 ? 128 : 0) + fg * 8;
  {
    const unsigned short* kg = Kpad + (size_t)kimg0 * (64 * INNER);
#pragma unroll
    for (int j = 0; j < 3; j++) gld16(kg + goK[j], Ks + lo[j]);
  }
  for (int fi = 0; fi < 8; fi++) {
    const int f = fg * 8 + fi;
    __syncthreads();   // (1) drains K[fi]; prev PV done by all waves
    {
      const unsigned short* vg = Vt + (size_t)(kimg0 + fi) * (INNER * 64);
#pragma unroll
      for (int j = 0; j < 3; j++) gld16(vg + goV[j], VtS + lo[j]);
    }
    f32x4 s4[2][4] = {{z4, z4, z4, z4}, {z4, z4, z4, z4}};
    __builtin_amdgcn_s_setprio(1);
#pragma unroll
    for (int ks = 0; ks < 3; ks++) {
#pragma unroll
      for (int kt = 0; kt < 4; kt++) {
        bf16x8 a = *(const bf16x8*)(Ks + kt * (16 * INNER) + rdK[ks]);
        s4[0][kt] = __builtin_amdgcn_mfma_f32_16x16x32_bf16(a, qf[0][ks], s4[0][kt], 0, 0, 0);
        s4[1][kt] = __builtin_amdgcn_mfma_f32_16x16x32_bf16(a, qf[1][ks], s4[1][kt], 0, 0, 0);
      }
    }
    __builtin_amdgcn_s_setprio(0);
#pragma unroll
    for (int qt = 0; qt < 2; qt++)
#pragma unroll
      for (int kt = 0; kt < 4; kt++) {
        float e0 = __builtin_exp2f(s4[qt][kt][0]);
        float e1 = __builtin_exp2f(s4[qt][kt][1]);
        float e2 = __builtin_exp2f(s4[qt][kt][2]);
        float e3 = __builtin_exp2f(s4[qt][kt][3]);
        unsigned lopk, hipk;
        asm("v_cvt_pk_bf16_f32 %0, %1, %2" : "=v"(lopk) : "v"(e0), "v"(e1));
        asm("v_cvt_pk_bf16_f32 %0, %1, %2" : "=v"(hipk) : "v"(e2), "v"(e3));
        uint2 pk = make_uint2(lopk, hipk);
        int row = qt * 16 + lr;
        int ch = (2 * kt + (lq >> 1)) ^ (row & 7);
        *(uint2*)(Pw + row * 64 + ch * 8 + (lq & 1) * 4) = pk;
      }
    __syncthreads();   // (2) drains Vt[fi]; all waves' K reads done
    if (fi < 7) {
      const unsigned short* kg = Kpad + (size_t)(kimg0 + fi + 1) * (64 * INNER);
#pragma unroll
      for (int j = 0; j < 3; j++) gld16(kg + goK[j], Ks + lo[j]);
    }
    f32x4 pv[2][6] = {{z4, z4, z4, z4, z4, z4}, {z4, z4, z4, z4, z4, z4}};
    __builtin_amdgcn_s_setprio(1);
#pragma unroll
    for (int ks = 0; ks < 2; ks++) {
      int row0 = 0 * 16 + lr, row1 = 1 * 16 + lr;
      int ch0 = ((ks * 4 + lq) ^ (row0 & 7));
      int ch1 = ((ks * 4 + lq) ^ (row1 & 7));
      bf16x8 b0 = *(const bf16x8*)(Pw + row0 * 64 + ch0 * 8);
      bf16x8 b1 = *(const bf16x8*)(Pw + row1 * 64 + ch1 * 8);
#pragma unroll
      for (int et = 0; et < 6; et++) {
        bf16x8 a = *(const bf16x8*)(VtS + et * (16 * 64) + rdV[ks]);
        pv[0][et] = __builtin_amdgcn_mfma_f32_16x16x32_bf16(a, b0, pv[0][et], 0, 0, 0);
        pv[1][et] = __builtin_amdgcn_mfma_f32_16x16x32_bf16(a, b1, pv[1][et], 0, 0, 0);
      }
    }
    __builtin_amdgcn_s_setprio(0);
#pragma unroll
    for (int qt = 0; qt < 2; qt++) {
      f32x2 dp = {0.f, 0.f}, np = {0.f, 0.f};
#pragma unroll
      for (int et = 0; et < 6; et++) {
        f32x2 al0 = __builtin_shufflevector(pv[qt][et], pv[qt][et], 0, 1);
        f32x2 al1 = __builtin_shufflevector(pv[qt][et], pv[qt][et], 2, 3);
        asm("v_pk_fma_f32 %0, %1, %2, %0" : "+v"(dp) : "v"(al0), "v"(rv2[qt][et][0]));
        asm("v_pk_fma_f32 %0, %1, %2, %0" : "+v"(np) : "v"(al0), "v"(al0));
        asm("v_pk_fma_f32 %0, %1, %2, %0" : "+v"(dp) : "v"(al1), "v"(rv2[qt][et][1]));
        asm("v_pk_fma_f32 %0, %1, %2, %0" : "+v"(np) : "v"(al1), "v"(al1));
      }
      float d = dp[0] + dp[1], nn = np[0] + np[1];
      d += __shfl_xor(d, 16, 64);  d += __shfl_xor(d, 32, 64);
      nn += __shfl_xor(nn, 16, 64); nn += __shfl_xor(nn, 32, 64);
      if (lane < 16) {
        float cv = d * __frsqrt_rn(fmaxf(nn, 1e-40f)) * invvn[qt];
        cosbuf[(size_t)(dir * 128 + f) * NSIDE + r0 + w * 32 + qt * 16 + lr] = cv;
      }
    }
  }
}

// ---------------------------------------------------------------------------
// reduce_out: out[bb*128+aa] = (sum_q cos0[bb][aa*49+q] + cos1[aa][bb*49+q])/49
// ---------------------------------------------------------------------------
__global__ __launch_bounds__(256) void reduce_out(const float* __restrict__ cosbuf,
                                                  float* __restrict__ out) {
  const int t = threadIdx.x, lane = t & 63, wv = t >> 6;
  const int pair = blockIdx.x * 4 + wv;
  const int bb = pair >> 7, aa = pair & 127;
  float v = 0.f;
  if (lane < S49) {
    v  = cosbuf[(size_t)bb * NSIDE + aa * S49 + lane];
    v += cosbuf[(size_t)(128 + aa) * NSIDE + bb * S49 + lane];
  }
  for (int m = 1; m < 64; m <<= 1) v += __shfl_xor(v, m, 64);
  if (lane == 0) out[pair] = v * (1.f / 49.f);
}

// ---------------------------------------------------------------------------
extern "C" void kernel_launch(void* const* d_in, const int* in_sizes, int n_in,
                              void* d_out, int out_size, void* d_ws, size_t ws_size,
                              hipStream_t stream) {
  const float* fa  = (const float*)d_in[0];
  const float* fb  = (const float*)d_in[1];
  const float* W1[3] = {(const float*)d_in[2], (const float*)d_in[4], (const float*)d_in[6]};
  const float* W2[3] = {(const float*)d_in[3], (const float*)d_in[5], (const float*)d_in[7]};
  float* out = (float*)d_out;

  unsigned short* p = (unsigned short*)d_ws;
  unsigned short* Xbf = p;                 p += (size_t)MROWS * CDIM;      // 19.3 MB
  unsigned short* W1T = p;                 p += (size_t)3 * CDIM * CDIM;   // 3.5 MB
  unsigned short* W2T = p;                 p += (size_t)3 * INNER * CDIM;  // 0.44 MB
  unsigned short* QKV = p;                 p += (size_t)3 * MROWS * INNER; // 7.2 MB
  unsigned short* Vt  = p;                 p += (size_t)256 * INNER * 64;  // 3.1 MB
  unsigned short* Kpad = p;                p += (size_t)256 * 64 * INNER;  // 3.1 MB (adjacent to Vt!)
  float* vnorm = (float*)p;                p += (size_t)MROWS * 2;         // 50 KB
  float* cosbuf = (float*)p;               p += (size_t)256 * NSIDE * 2;   // 6.4 MB
  unsigned short* H = p;                   p += (size_t)3 * MROWS * CDIM;  // 57.8 MB (batched)
  const size_t need_batched = (size_t)(p - (unsigned short*)d_ws) * 2;
  const int batched = ws_size >= need_batched;

  prep_all<<<dim3(5112), 256, 0, stream>>>(fa, fb, W1[0], W1[1], W1[2],
                                           W2[0], W2[1], W2[2],
                                           Xbf, W1T, W2T, Vt /* VtKpad span */);
  if (batched) {
    gemm1_8p<<<dim3(CDIM / 256, MROWS / 256, 3), 512, 0, stream>>>(Xbf, W1T, H, 0, 1);
    gemm2b5<<<dim3(MROWS / 64, 3), 512, 0, stream>>>(H, W2T, QKV, Kpad, Vt, vnorm, 0, 1);
  } else {
    for (int wdx = 0; wdx < 3; wdx++) {
      gemm1_8p<<<dim3(CDIM / 256, MROWS / 256, 1), 512, 0, stream>>>(Xbf, W1T, H, wdx, 0);
      gemm2b5<<<dim3(MROWS / 64, 1), 512, 0, stream>>>(H, W2T, QKV, Kpad, Vt, vnorm, wdx, 0);
    }
  }
  attn13<<<dim3(2 * 784), 256, 0, stream>>>(
      QKV, Kpad, QKV + (size_t)2 * MROWS * INNER, Vt, vnorm, cosbuf);
  reduce_out<<<dim3(4096), 256, 0, stream>>>(cosbuf, out);
}